// Round 14
// baseline (289.079 us; speedup 1.0000x reference)
//
#include <hip/hip_runtime.h>
#include <hip/hip_bf16.h>

// Problem constants
constexpr int Bc  = 4;
constexpr int Sc  = 2048;
constexpr int Dc  = 1024;
constexpr int Hc  = 16;
constexpr int DKc = 64;
constexpr int Mc  = Bc * Sc;      // 8192 token rows

typedef __bf16 bf16x8 __attribute__((ext_vector_type(8)));
typedef float  f32x4  __attribute__((ext_vector_type(4)));
typedef unsigned short ushort_t;

#define DEV __device__ __forceinline__

DEV unsigned short f2bf(float f) {
    unsigned u = __builtin_bit_cast(unsigned, f);
    u += 0x7FFFu + ((u >> 16) & 1u);            // RNE
    return (unsigned short)(u >> 16);
}
DEV unsigned pack2(float a, float b) {
    return (unsigned)f2bf(a) | ((unsigned)f2bf(b) << 16);
}
// async global->LDS, 16B per lane; LDS dest = wave-uniform base + lane*16
DEV void gl16(const void* g, void* l) {
    __builtin_amdgcn_global_load_lds((const __attribute__((address_space(1))) unsigned int*)g,
                                     (__attribute__((address_space(3))) unsigned int*)l, 16, 0, 0);
}
DEV f32x4 mfma16(bf16x8 a, bf16x8 b, f32x4 c) {
    return __builtin_amdgcn_mfma_f32_16x16x32_bf16(a, b, c, 0, 0, 0);
}
// spread 8 bits: bit t -> bit 4t
DEV unsigned spread4(unsigned x) {
    x = (x | (x << 12)) & 0x000F000Fu;
    x = (x | (x << 6))  & 0x03030303u;
    x = (x | (x << 3))  & 0x11111111u;
    return x;
}

// k-permutation bookkeeping (kn rows + mask bits stored permuted so that
// attn's in-register P fragments line up with NATURAL-order V):
//   stored p holds natural n = pi(p);  pi(p) = p4<<5 | p3:2<<3 | p5<<2 | p1:0
//   pi preserves the low 2 bits -> 4 consecutive stored bits = 4 consecutive
//   natural ints (int4-loadable in the mask pack).

// ---------------------------------------------------------------------------
// fold_w2 (separate kernel — r11: merging its 16KB LDS + wr[64] into the
// streaming kernel costs 4x BW):
__global__ __launch_bounds__(256) void fold_w2(const float* __restrict__ naqw,
                                               const float* __restrict__ wq,
                                               unsigned short* __restrict__ wqf,
                                               const float* __restrict__ nakw,
                                               const float* __restrict__ wk,
                                               unsigned short* __restrict__ wkf,
                                               const float* __restrict__ bq,
                                               const float* __restrict__ naqb,
                                               float* __restrict__ bqf,
                                               const float* __restrict__ bk,
                                               const float* __restrict__ nakb,
                                               float* __restrict__ bkf) {
    const int colg = blockIdx.x, h = blockIdx.y, z = blockIdx.z;
    if (z == 2) {
        if (h >= 2) return;
        const float* na = h ? nakw : naqw;
        const float* b  = h ? bk : bq;
        const float* nb = h ? nakb : naqb;
        float* out      = h ? bkf : bqf;
        int idx = colg * 256 + threadIdx.x;
        if (idx >= Dc) return;
        int hh = idx >> 6, i = idx & 63;
        float acc = nb[i];
        for (int t = 0; t < DKc; ++t) acc += na[i * DKc + t] * b[hh * DKc + t];
        out[idx] = acc;
        return;
    }
    const float* na = z ? nakw : naqw;
    const float* w  = z ? wk : wq;
    unsigned short* out = z ? wkf : wqf;
    const int col = colg * 256 + threadIdx.x;

    __shared__ float nal[64 * 64];
    for (int i = threadIdx.x; i < 4096; i += 256) nal[i] = na[i];

    float wr[64];
#pragma unroll
    for (int t = 0; t < 64; ++t) wr[t] = w[(h * 64 + t) * Dc + col];
    __syncthreads();

    for (int i = 0; i < 64; ++i) {
        float acc = 0.f;
#pragma unroll
        for (int t = 0; t < 64; ++t) acc += nal[i * 64 + t] * wr[t];
        out[(h * 64 + i) * Dc + col] = f2bf(acc);
    }
}

// ---------------------------------------------------------------------------
// conv_mask (LEAN: no LDS, low VGPR):
constexpr int CONVB = (3 * Mc * Dc + 2 * Dc * Dc) / 8 / 256;   // 13312
constexpr int MASKB = Bc * Sc * Sc / 1024;                      // 16384
__global__ __launch_bounds__(256) void conv_mask(const float* __restrict__ Q,
                                                 const float* __restrict__ K,
                                                 const float* __restrict__ V,
                                                 const float* __restrict__ wv,
                                                 const float* __restrict__ wo,
                                                 ushort_t* __restrict__ qb,
                                                 ushort_t* __restrict__ kb,
                                                 ushort_t* __restrict__ vb,
                                                 ushort_t* __restrict__ wvf,
                                                 ushort_t* __restrict__ wof,
                                                 const int* __restrict__ m,
                                                 unsigned* __restrict__ mbits) {
    const int bid = blockIdx.x;
    const int tid = threadIdx.x;
    if (bid < CONVB) {
        size_t i = ((size_t)bid * 256 + tid) * 8;
        constexpr size_t N = (size_t)Mc * Dc;   // 8M
        constexpr size_t W = (size_t)Dc * Dc;   // 1M
        const float* src; ushort_t* dst; size_t off;
        if      (i < N)         { src = Q;  dst = qb;  off = i; }
        else if (i < 2 * N)     { src = K;  dst = kb;  off = i - N; }
        else if (i < 3 * N)     { src = V;  dst = vb;  off = i - 2 * N; }
        else if (i < 3 * N + W) { src = wv; dst = wvf; off = i - 3 * N; }
        else                    { src = wo; dst = wof; off = i - 3 * N - W; }
        float4 a = *(const float4*)(src + off), b = *(const float4*)(src + off + 4);
        uint4 o;
        o.x = pack2(a.x, a.y); o.y = pack2(a.z, a.w);
        o.z = pack2(b.x, b.y); o.w = pack2(b.z, b.w);
        *(uint4*)(dst + off) = o;
    } else {
        const int mb = bid - CONVB;                       // 0..MASKB-1
        const size_t p0 = ((size_t)mb * 256 + tid) * 4;   // stored bit base (mult of 4)
        const int ing = (int)(p0 & 63);                   // in-group offset (mult of 4)
        const int nat = (((ing >> 4) & 1) << 5) | (((ing >> 2) & 3) << 3)
                      | (((ing >> 5) & 1) << 2);          // low 2 bits zero
        const int4 mv = *(const int4*)(m + ((p0 & ~(size_t)63) | (size_t)nat));
        unsigned nib = (unsigned)(mv.x != 0) | ((unsigned)(mv.y != 0) << 1)
                     | ((unsigned)(mv.z != 0) << 2) | ((unsigned)(mv.w != 0) << 3);
        unsigned long long bal0 = __ballot((nib & 1u) != 0);
        unsigned long long bal1 = __ballot((nib & 2u) != 0);
        unsigned long long bal2 = __ballot((nib & 4u) != 0);
        unsigned long long bal3 = __ballot((nib & 8u) != 0);
        const int lane = tid & 63, s = tid >> 6;
        const int sh8 = (lane & 7) * 8;                   // safe shift (<64)
        unsigned bb0 = (unsigned)(bal0 >> sh8) & 0xFFu;
        unsigned bb1 = (unsigned)(bal1 >> sh8) & 0xFFu;
        unsigned bb2 = (unsigned)(bal2 >> sh8) & 0xFFu;
        unsigned bb3 = (unsigned)(bal3 >> sh8) & 0xFFu;
        unsigned word = spread4(bb0) | (spread4(bb1) << 1)
                      | (spread4(bb2) << 2) | (spread4(bb3) << 3);
        if (lane < 8) mbits[(size_t)mb * 32 + s * 8 + lane] = word;
    }
}

// ---------------------------------------------------------------------------
// gemm_bt: 128x128 tile 2-phase dbuf (for vt and out GEMMs — only 128 tiles
// each, 256-sq would idle half the CUs).
// EPI 1: acc+bias[row] -> vt tiles [B,H][kt:16][dk:64][128], XOR
// EPI 2: acc+bias[col] -> fp32 merged [M,N]
template <int EPI, int SWZ>
__global__ __launch_bounds__(256) void gemm_bt(const ushort_t* __restrict__ A,
                                               const ushort_t* __restrict__ B,
                                               const float* __restrict__ bias,
                                               void* __restrict__ outp,
                                               int Mdim, int Ndim, int Kdim) {
    __shared__ __align__(16) unsigned char As[2][16384];   // [buf][row:128][128B]
    __shared__ __align__(16) unsigned char Bs[2][16384];

    int bx = blockIdx.x, by = blockIdx.y;
    {
        int nwg = gridDim.x * gridDim.y;
        int L = by * gridDim.x + bx;
        int cpx = nwg >> 3;
        int orig = (L & 7) * cpx + (L >> 3);
        if constexpr (SWZ == 1) { bx = orig % gridDim.x; by = orig / gridDim.x; }
        else                    { by = orig % gridDim.y; bx = orig / gridDim.y; }
    }

    const int tid = threadIdx.x, lane = tid & 63, wave = tid >> 6;
    const int wr = wave >> 1, wc = wave & 1;
    const int q = lane & 15, g = lane >> 4;
    const int m0 = by * 128, n0 = bx * 128;

    const int strow = lane >> 3, stcol = (lane & 7) * 8;
    const ushort_t* Ab = A + (size_t)(m0 + strow) * Kdim + stcol;
    const ushort_t* Bb = B + (size_t)(n0 + strow) * Kdim + stcol;

    f32x4 acc[4][4] = {};
    const int nK = Kdim >> 6;

#pragma unroll
    for (int i = 0; i < 4; ++i) {
        const int ro = (wave * 4 + i) * 8;
        gl16(Ab + (size_t)ro * Kdim, As[0] + (wave * 4 + i) * 1024);
        gl16(Bb + (size_t)ro * Kdim, Bs[0] + (wave * 4 + i) * 1024);
    }
    __syncthreads();

    for (int kt = 0; kt < nK; ++kt) {
        const int cur = kt & 1;
        if (kt + 1 < nK) {
            const int k1 = (kt + 1) << 6;
#pragma unroll
            for (int i = 0; i < 4; ++i) {
                const int ro = (wave * 4 + i) * 8;
                gl16(Ab + (size_t)ro * Kdim + k1, As[cur ^ 1] + (wave * 4 + i) * 1024);
                gl16(Bb + (size_t)ro * Kdim + k1, Bs[cur ^ 1] + (wave * 4 + i) * 1024);
            }
        }
#pragma unroll
        for (int s = 0; s < 2; ++s) {
            const int cb = s * 64 + g * 16;
            bf16x8 a[4], b[4];
#pragma unroll
            for (int m = 0; m < 4; ++m)
                a[m] = *(const bf16x8*)(As[cur] + (wr * 64 + m * 16 + q) * 128 + cb);
#pragma unroll
            for (int n = 0; n < 4; ++n)
                b[n] = *(const bf16x8*)(Bs[cur] + (wc * 64 + n * 16 + q) * 128 + cb);
#pragma unroll
            for (int m = 0; m < 4; ++m)
#pragma unroll
                for (int n = 0; n < 4; ++n)
                    acc[m][n] = mfma16(a[m], b[n], acc[m][n]);
        }
        __syncthreads();
    }

#pragma unroll
    for (int m = 0; m < 4; ++m)
#pragma unroll
        for (int n = 0; n < 4; ++n) {
            int gn = n0 + wc * 64 + n * 16 + q;
#pragma unroll
            for (int r = 0; r < 4; ++r) {
                int gm = m0 + wr * 64 + m * 16 + (g << 2) + r;
                float v = acc[m][n][r];
                if constexpr (EPI == 1) {
                    v += bias[gm];
                    int hh = gm >> 6, dk = gm & 63, b = gn >> 11, s = gn & 2047;
                    int kt2 = s >> 7, kloc = s & 127;
                    int eofs = ((kloc * 2) ^ ((dk & 7) << 4)) >> 1;
                    size_t idx = ((size_t)(b * Hc + hh)) * Sc * DKc + (size_t)kt2 * 8192 + dk * 128 + eofs;
                    ((unsigned short*)outp)[idx] = f2bf(v);
                } else {
                    v += bias[gn];
                    ((float*)outp)[(size_t)gm * Ndim + gn] = v;
                }
            }
        }
}

// ---------------------------------------------------------------------------
// gemm_qk256: qn+kn projections, 256x256 tile, BK=64, 8 waves (2x4, each
// 128x64 out, acc[8][4]), 128KB LDS 2-phase dbuf, grid (4,32,2) = 256 blocks
// = 1/CU. Intensity 128B staged per MFMA inst (vs 256B at 128-sq) flips the
// K-loop compute-bound (m248: 666 TF @ K=1024 for this config vs our 520).
__global__ __launch_bounds__(512, 2) void gemm_qk256(const ushort_t* __restrict__ qb,
                                                     const ushort_t* __restrict__ wqf,
                                                     const float* __restrict__ bqf,
                                                     ushort_t* __restrict__ qnb,
                                                     const ushort_t* __restrict__ kb,
                                                     const ushort_t* __restrict__ wkf,
                                                     const float* __restrict__ bkf,
                                                     ushort_t* __restrict__ knb,
                                                     const float* __restrict__ temp) {
    __shared__ __align__(16) unsigned char As[2][32768];   // [buf][row:256][128B]
    __shared__ __align__(16) unsigned char Bs[2][32768];

    const int zz = blockIdx.z;
    const ushort_t* A = zz ? kb : qb;
    const ushort_t* B = zz ? wkf : wqf;
    const float* bias = zz ? bkf : bqf;

    // XCD chunk within this z: 128 blocks, cpx=16
    int L = blockIdx.y * gridDim.x + blockIdx.x;    // x=4 (N tiles), y=32 (M tiles)
    int orig = (L & 7) * 16 + (L >> 3);
    int bx = orig & 3, by = orig >> 2;

    const int tid = threadIdx.x, lane = tid & 63, wave = tid >> 6;
    const int wr = wave >> 2, wc = wave & 3;        // 2 x 4 wave grid
    const int q = lane & 15, g = lane >> 4;
    const int m0 = by * 256, n0 = bx * 256;

    const int strow = lane >> 3, stcol = (lane & 7) * 8;
    const ushort_t* Ab = A + (size_t)(m0 + strow) * Dc + stcol;
    const ushort_t* Bb = B + (size_t)(n0 + strow) * Dc + stcol;

    f32x4 acc[8][4] = {};
    constexpr int nK = Dc >> 6;   // 16

#define STAGE256(buf, k0)                                                       \
    {                                                                           \
        _Pragma("unroll")                                                       \
        for (int i = 0; i < 4; ++i) {                                           \
            const int j = wave * 4 + i;                                         \
            gl16(Ab + (size_t)(j * 8) * Dc + (k0), As[buf] + j * 1024);         \
            gl16(Bb + (size_t)(j * 8) * Dc + (k0), Bs[buf] + j * 1024);         \
        }                                                                       \
    }

    STAGE256(0, 0);
    __syncthreads();

    for (int kt = 0; kt < nK; ++kt) {
        const int cur = kt & 1;
        if (kt + 1 < nK) STAGE256(cur ^ 1, (kt + 1) << 6);
#pragma unroll
        for (int s = 0; s < 2; ++s) {
            const int cb = s * 64 + g * 16;
            bf16x8 a[8], b[4];
#pragma unroll
            for (int m = 0; m < 8; ++m)
                a[m] = *(const bf16x8*)(As[cur] + (wr * 128 + m * 16 + q) * 128 + cb);
#pragma unroll
            for (int n = 0; n < 4; ++n)
                b[n] = *(const bf16x8*)(Bs[cur] + (wc * 64 + n * 16 + q) * 128 + cb);
#pragma unroll
            for (int m = 0; m < 8; ++m)
#pragma unroll
                for (int n = 0; n < 4; ++n)
                    acc[m][n] = mfma16(a[m], b[n], acc[m][n]);
        }
        __syncthreads();   // drains vmcnt (next buf staged) + reads of cur done
    }
#undef STAGE256

    // Epilogue. C/D layout: row=(lane>>4)*4+r, col=lane&15.
#pragma unroll
    for (int m = 0; m < 8; ++m)
#pragma unroll
        for (int n = 0; n < 4; ++n) {
            int gn = n0 + wc * 64 + n * 16 + q;
            float sc_h = 1.f;
            if (zz == 0) sc_h = 0.18033688011112042f * __builtin_amdgcn_rcpf(temp[gn >> 6]);
#pragma unroll
            for (int r = 0; r < 4; ++r) {
                int gm = m0 + wr * 128 + m * 16 + (g << 2) + r;
                float v = tanhf(acc[m][n][r] + bias[gn]);
                int b = gm >> 11, s = gm & 2047, hh = gn >> 6, dk = gn & 63;
                if (zz == 0) {
                    qnb[(((size_t)(b * Hc + hh)) * Sc + s) * DKc + dk] = f2bf(v * sc_h);
                } else {
                    int kt2 = s >> 7, nr = s & 127;
                    int prow = (nr & 64) | (((nr >> 5) & 1) << 4) | (((nr >> 3) & 3) << 2)
                             | (((nr >> 2) & 1) << 5) | (nr & 3);
                    int eofs = ((dk * 2) ^ ((prow & 7) << 4)) >> 1;
                    size_t idx = ((size_t)(b * Hc + hh)) * Sc * DKc + (size_t)kt2 * 8192 + prow * 64 + eofs;
                    knb[idx] = f2bf(v);
                }
            }
        }
}

// ---------------------------------------------------------------------------
// Flash attention (unchanged — issue-saturated at MfmaUtil+VALUBusy ~93%).
__global__ __launch_bounds__(512, 2) void attn_k(const ushort_t* __restrict__ qn,
                                                 const ushort_t* __restrict__ kn,
                                                 const ushort_t* __restrict__ vtp,
                                                 const unsigned* __restrict__ mbits,
                                                 ushort_t* __restrict__ ctxb) {
    __shared__ __align__(16) unsigned char Kl[2][16384];   // [buf][prow:128][128B swz]
    __shared__ __align__(16) unsigned char Vl[2][16384];   // [buf][dk:64][256B swz]

    const int tid = threadIdx.x, lane = tid & 63, wave = tid >> 6;
    const int q = lane & 15, g = lane >> 4;

    const int wg = blockIdx.x;
    const int orig = (wg & 7) * 64 + (wg >> 3);
    const int qt = orig & 7, h = (orig >> 3) & 15, b = orig >> 7;
    const int q0 = qt * 256;
    const int qr0 = q0 + wave * 32 + q;
    const size_t headoff = ((size_t)(b * Hc + h)) * Sc * DKc;

    const unsigned char* Ksrc = (const unsigned char*)(kn + headoff);
    const unsigned char* Vsrc = (const unsigned char*)(vtp + headoff);
    const int so = wave * 1024 + lane * 16;
    const int ld = wave * 1024;

    bf16x8 qf[2][2];
    {
        const ushort_t* p0 = qn + headoff + (size_t)qr0 * DKc + g * 8;
        qf[0][0] = *(const bf16x8*)p0;
        qf[0][1] = *(const bf16x8*)(p0 + 32);
        qf[1][0] = *(const bf16x8*)(p0 + 16 * DKc);
        qf[1][1] = *(const bf16x8*)(p0 + 16 * DKc + 32);
    }
    const unsigned* mr0 = mbits + ((size_t)b * Sc + qr0) * (Sc / 32);
    const unsigned* mr1 = mr0 + 16 * (Sc / 32);

    bf16x8 ones;
#pragma unroll
    for (int i = 0; i < 8; ++i) ones[i] = (__bf16)1.0f;

    f32x4 ctxa[2][4] = {};
    f32x4 lacc[2] = {};
    const int swz = (q & 7) << 4;
    const int sh = g << 2;

    gl16(Ksrc + so,        &Kl[0][ld]);
    gl16(Ksrc + 8192 + so, &Kl[0][8192 + ld]);
    gl16(Vsrc + so,        &Vl[0][ld]);
    gl16(Vsrc + 8192 + so, &Vl[0][8192 + ld]);
    __syncthreads();

    for (int kt = 0; kt < Sc / 128; ++kt) {
        const int cur = kt & 1;
        if (kt < Sc / 128 - 1) {
            const unsigned char* ks = Ksrc + (kt + 1) * 16384;
            const unsigned char* vs = Vsrc + (kt + 1) * 16384;
            gl16(ks + so,        &Kl[cur ^ 1][ld]);
            gl16(ks + 8192 + so, &Kl[cur ^ 1][8192 + ld]);
            gl16(vs + so,        &Vl[cur ^ 1][ld]);
            gl16(vs + 8192 + so, &Vl[cur ^ 1][8192 + ld]);
        }
        unsigned mwq[2][4];
        {
            uint4 t0 = *(const uint4*)(mr0 + kt * 4);
            uint4 t1 = *(const uint4*)(mr1 + kt * 4);
            mwq[0][0] = t0.x >> sh; mwq[0][1] = t0.y >> sh;
            mwq[0][2] = t0.z >> sh; mwq[0][3] = t0.w >> sh;
            mwq[1][0] = t1.x >> sh; mwq[1][1] = t1.y >> sh;
            mwq[1][2] = t1.z >> sh; mwq[1][3] = t1.w >> sh;
        }
        const unsigned char* Kb = Kl[cur];
        const unsigned char* Vb = Vl[cur];

#pragma unroll
        for (int kh = 0; kh < 2; ++kh) {
            f32x4 s0[4] = {}, s1[4] = {};
            __builtin_amdgcn_s_setprio(1);
#pragma unroll
            for (int f = 0; f < 4; ++f) {
                const int ro = (kh * 64 + f * 16 + q) * 128;
                bf16x8 a0 = *(const bf16x8*)(Kb + ro + ((g * 16) ^ swz));
                bf16x8 a1 = *(const bf16x8*)(Kb + ro + ((64 + g * 16) ^ swz));
                s0[f] = mfma16(a0, qf[0][0], s0[f]);
                s0[f] = mfma16(a1, qf[0][1], s0[f]);
                s1[f] = mfma16(a0, qf[1][0], s1[f]);
                s1[f] = mfma16(a1, qf[1][1], s1[f]);
            }
            __builtin_amdgcn_s_setprio(0);

#pragma unroll
            for (int f = 0; f < 4; ++f) {
                unsigned w0 = mwq[0][kh * 2 + (f >> 1)];
                unsigned w1 = mwq[1][kh * 2 + (f >> 1)];
#pragma unroll
                for (int r = 0; r < 4; ++r) {
                    const unsigned bitc = 1u << (((f & 1) << 4) + r);
                    float v0 = (w0 & bitc) ? s0[f][r] : -1e30f;
                    float v1 = (w1 & bitc) ? s1[f][r] : -1e30f;
                    s0[f][r] = __builtin_amdgcn_exp2f(v0);
                    s1[f][r] = __builtin_amdgcn_exp2f(v1);
                }
            }

            bf16x8 pa0[2], pa1[2];
#pragma unroll
            for (int cs = 0; cs < 2; ++cs)
#pragma unroll
                for (int r = 0; r < 4; ++r) {
                    pa0[cs][r]     = (__bf16)s0[cs][r];
                    pa0[cs][4 + r] = (__bf16)s0[cs + 2][r];
                    pa1[cs][r]     = (__bf16)s1[cs][r];
                    pa1[cs][4 + r] = (__bf16)s1[cs + 2][r];
                }

            __builtin_amdgcn_s_setprio(1);
#pragma unroll
            for (int cs = 0; cs < 2; ++cs) {
                const int csg = kh * 2 + cs;
                lacc[0] = mfma16(pa0[cs], ones, lacc[0]);
                lacc[1] = mfma16(pa1[cs], ones, lacc[1]);
#pragma unroll
                for (int j = 0; j < 4; ++j) {
                    bf16x8 vb = *(const bf16x8*)(Vb + (j * 16 + q) * 256 + ((csg * 64 + g * 16) ^ swz));
                    ctxa[0][j] = mfma16(pa0[cs], vb, ctxa[0][j]);
                    ctxa[1][j] = mfma16(pa1[cs], vb, ctxa[1][j]);
                }
            }
            __builtin_amdgcn_s_setprio(0);
        }
        __syncthreads();
    }

#pragma unroll
    for (int qg = 0; qg < 2; ++qg) {
        f32x4 linv;
#pragma unroll
        for (int r = 0; r < 4; ++r) linv[r] = __builtin_amdgcn_rcpf(lacc[qg][r]);
#pragma unroll
        for (int j = 0; j < 4; ++j)
#pragma unroll
            for (int r = 0; r < 4; ++r) {
                int srow = q0 + wave * 32 + qg * 16 + (g << 2) + r;
                int col = h * DKc + j * 16 + q;
                float v = ctxa[qg][j][r] * linv[r];
                ctxb[((size_t)b * Sc + srow) * Dc + col] = __builtin_bit_cast(unsigned short, (__bf16)v);
            }
    }
}

// ---------------------------------------------------------------------------
__global__ __launch_bounds__(256) void rmsnorm_k(float* __restrict__ out,
                                                 const float* __restrict__ w) {
    const int row = blockIdx.x, tid = threadIdx.x;
    float4* p = (float4*)(out + (size_t)row * Dc) + tid;
    float4 v = *p;
    float ss = v.x * v.x + v.y * v.y + v.z * v.z + v.w * v.w;
#pragma unroll
    for (int o = 32; o >= 1; o >>= 1) ss += __shfl_xor(ss, o);
    __shared__ float sm[4];
    if ((tid & 63) == 0) sm[tid >> 6] = ss;
    __syncthreads();
    float tot = sm[0] + sm[1] + sm[2] + sm[3];
    float r = rsqrtf(tot * (1.f / Dc) + 1e-8f);
    float4 wv = *((const float4*)w + tid);
    v.x *= r * wv.x; v.y *= r * wv.y; v.z *= r * wv.z; v.w *= r * wv.w;
    *p = v;
}

// ---------------------------------------------------------------------------
extern "C" void kernel_launch(void* const* d_in, const int* in_sizes, int n_in,
                              void* d_out, int out_size, void* d_ws, size_t ws_size,
                              hipStream_t stream) {
    (void)in_sizes; (void)n_in; (void)out_size; (void)ws_size;
    const float* Q    = (const float*)d_in[0];
    const float* K    = (const float*)d_in[1];
    const float* V    = (const float*)d_in[2];
    const int*   mask = (const int*)  d_in[3];
    const float* wq   = (const float*)d_in[4];
    const float* bq   = (const float*)d_in[5];
    const float* wk   = (const float*)d_in[6];
    const float* bk   = (const float*)d_in[7];
    const float* wv   = (const float*)d_in[8];
    const float* bv   = (const float*)d_in[9];
    const float* wo   = (const float*)d_in[10];
    const float* bo   = (const float*)d_in[11];
    const float* naqw = (const float*)d_in[12];
    const float* naqb = (const float*)d_in[13];
    const float* nakw = (const float*)d_in[14];
    const float* nakb = (const float*)d_in[15];
    const float* temp = (const float*)d_in[16];
    const float* rmsw = (const float*)d_in[17];

    char* ws = (char*)d_ws;
    size_t off = 0;
    auto take = [&](size_t n) { char* p = ws + off; off += (n + 255) & ~(size_t)255; return p; };
    unsigned short* vtb  = (unsigned short*)take((size_t)Mc * Dc * 2);
    unsigned short* qb   = (unsigned short*)take((size_t)Mc * Dc * 2);
    unsigned short* kb   = (unsigned short*)take((size_t)Mc * Dc * 2);
    unsigned short* vb   = (unsigned short*)take((size_t)Mc * Dc * 2);
    unsigned short* qnb  = (unsigned short*)take((size_t)Mc * Dc * 2);
    unsigned short* knb  = (unsigned short*)take((size_t)Mc * Dc * 2);
    unsigned short* wqf  = (unsigned short*)take((size_t)Dc * Dc * 2);
    unsigned short* wkf  = (unsigned short*)take((size_t)Dc * Dc * 2);
    unsigned short* wvf  = (unsigned short*)take((size_t)Dc * Dc * 2);
    unsigned short* wof  = (unsigned short*)take((size_t)Dc * Dc * 2);
    float*    bqf   = (float*)take(Dc * 4);
    float*    bkf   = (float*)take(Dc * 4);
    unsigned* mbits = (unsigned*)take((size_t)Bc * Sc * (Sc / 32) * 4);
    // alias (live ranges disjoint): ctxb reuses kb (kb dead after qk GEMM)
    unsigned short* ctxb = kb;

    fold_w2<<<dim3(4, 16, 3), 256, 0, stream>>>(naqw, wq, wqf, nakw, wk, wkf,
                                                bq, naqb, bqf, bk, nakb, bkf);
    conv_mask<<<dim3(CONVB + MASKB), 256, 0, stream>>>(Q, K, V, wv, wo,
                                                       qb, kb, vb, wvf, wof,
                                                       mask, mbits);

    // v^T = Wv @ V^T + bv   (tile layout for attn staging)
    gemm_bt<1, 2><<<dim3(Mc / 128, Dc / 128), 256, 0, stream>>>(
        wvf, vb, bv, vtb, Dc, Mc, Dc);
    // qn/kn projections, 256-sq tile (z=0: qn scaled; z=1: kn tiles)
    gemm_qk256<<<dim3(4, 32, 2), 512, 0, stream>>>(
        qb, wqf, bqf, qnb, kb, wkf, bkf, knb, temp);

    attn_k<<<dim3(512), 512, 0, stream>>>(qnb, knb, vtb, mbits, ctxb);

    // out = ctx @ wo^T + bo (fp32 into d_out), then in-place RMSNorm
    gemm_bt<2, 1><<<dim3(Dc / 128, Mc / 128), 256, 0, stream>>>(
        ctxb, wof, bo, d_out, Mc, Dc, Dc);
    rmsnorm_k<<<dim3(Mc), 256, 0, stream>>>((float*)d_out, rmsw);
}

// Round 15
// 258.642 us; speedup vs baseline: 1.1177x; 1.1177x over previous
//
#include <hip/hip_runtime.h>
#include <hip/hip_bf16.h>

// Problem constants
constexpr int Bc  = 4;
constexpr int Sc  = 2048;
constexpr int Dc  = 1024;
constexpr int Hc  = 16;
constexpr int DKc = 64;
constexpr int Mc  = Bc * Sc;      // 8192 token rows

typedef __bf16 bf16x8 __attribute__((ext_vector_type(8)));
typedef float  f32x4  __attribute__((ext_vector_type(4)));
typedef unsigned short ushort_t;

#define DEV __device__ __forceinline__

DEV unsigned short f2bf(float f) {
    unsigned u = __builtin_bit_cast(unsigned, f);
    u += 0x7FFFu + ((u >> 16) & 1u);            // RNE
    return (unsigned short)(u >> 16);
}
DEV unsigned pack2(float a, float b) {
    return (unsigned)f2bf(a) | ((unsigned)f2bf(b) << 16);
}
// async global->LDS, 16B per lane; LDS dest = wave-uniform base + lane*16
DEV void gl16(const void* g, void* l) {
    __builtin_amdgcn_global_load_lds((const __attribute__((address_space(1))) unsigned int*)g,
                                     (__attribute__((address_space(3))) unsigned int*)l, 16, 0, 0);
}
DEV f32x4 mfma16(bf16x8 a, bf16x8 b, f32x4 c) {
    return __builtin_amdgcn_mfma_f32_16x16x32_bf16(a, b, c, 0, 0, 0);
}
// counted vmcnt waits (T4): literal immediates, memory clobber + sched fence
DEV void wait_vm8() { asm volatile("s_waitcnt vmcnt(8)" ::: "memory"); __builtin_amdgcn_sched_barrier(0); }
DEV void wait_vm0() { asm volatile("s_waitcnt vmcnt(0)" ::: "memory"); __builtin_amdgcn_sched_barrier(0); }
// spread 8 bits: bit t -> bit 4t
DEV unsigned spread4(unsigned x) {
    x = (x | (x << 12)) & 0x000F000Fu;
    x = (x | (x << 6))  & 0x03030303u;
    x = (x | (x << 3))  & 0x11111111u;
    return x;
}

// k-permutation bookkeeping (kn rows + mask bits stored permuted so that
// attn's in-register P fragments line up with NATURAL-order V):
//   stored p holds natural n = pi(p);  pi(p) = p4<<5 | p3:2<<3 | p5<<2 | p1:0

// ---------------------------------------------------------------------------
// fold_w2 (separate kernel — r11: merging its 16KB LDS + wr[64] into the
// streaming kernel costs 4x BW):
__global__ __launch_bounds__(256) void fold_w2(const float* __restrict__ naqw,
                                               const float* __restrict__ wq,
                                               unsigned short* __restrict__ wqf,
                                               const float* __restrict__ nakw,
                                               const float* __restrict__ wk,
                                               unsigned short* __restrict__ wkf,
                                               const float* __restrict__ bq,
                                               const float* __restrict__ naqb,
                                               float* __restrict__ bqf,
                                               const float* __restrict__ bk,
                                               const float* __restrict__ nakb,
                                               float* __restrict__ bkf) {
    const int colg = blockIdx.x, h = blockIdx.y, z = blockIdx.z;
    if (z == 2) {
        if (h >= 2) return;
        const float* na = h ? nakw : naqw;
        const float* b  = h ? bk : bq;
        const float* nb = h ? nakb : naqb;
        float* out      = h ? bkf : bqf;
        int idx = colg * 256 + threadIdx.x;
        if (idx >= Dc) return;
        int hh = idx >> 6, i = idx & 63;
        float acc = nb[i];
        for (int t = 0; t < DKc; ++t) acc += na[i * DKc + t] * b[hh * DKc + t];
        out[idx] = acc;
        return;
    }
    const float* na = z ? nakw : naqw;
    const float* w  = z ? wk : wq;
    unsigned short* out = z ? wkf : wqf;
    const int col = colg * 256 + threadIdx.x;

    __shared__ float nal[64 * 64];
    for (int i = threadIdx.x; i < 4096; i += 256) nal[i] = na[i];

    float wr[64];
#pragma unroll
    for (int t = 0; t < 64; ++t) wr[t] = w[(h * 64 + t) * Dc + col];
    __syncthreads();

    for (int i = 0; i < 64; ++i) {
        float acc = 0.f;
#pragma unroll
        for (int t = 0; t < 64; ++t) acc += nal[i * 64 + t] * wr[t];
        out[(h * 64 + i) * Dc + col] = f2bf(acc);
    }
}

// ---------------------------------------------------------------------------
// conv_mask (LEAN: no LDS, low VGPR):
constexpr int CONVB = (3 * Mc * Dc + 2 * Dc * Dc) / 8 / 256;   // 13312
constexpr int MASKB = Bc * Sc * Sc / 1024;                      // 16384
__global__ __launch_bounds__(256) void conv_mask(const float* __restrict__ Q,
                                                 const float* __restrict__ K,
                                                 const float* __restrict__ V,
                                                 const float* __restrict__ wv,
                                                 const float* __restrict__ wo,
                                                 ushort_t* __restrict__ qb,
                                                 ushort_t* __restrict__ kb,
                                                 ushort_t* __restrict__ vb,
                                                 ushort_t* __restrict__ wvf,
                                                 ushort_t* __restrict__ wof,
                                                 const int* __restrict__ m,
                                                 unsigned* __restrict__ mbits) {
    const int bid = blockIdx.x;
    const int tid = threadIdx.x;
    if (bid < CONVB) {
        size_t i = ((size_t)bid * 256 + tid) * 8;
        constexpr size_t N = (size_t)Mc * Dc;   // 8M
        constexpr size_t W = (size_t)Dc * Dc;   // 1M
        const float* src; ushort_t* dst; size_t off;
        if      (i < N)         { src = Q;  dst = qb;  off = i; }
        else if (i < 2 * N)     { src = K;  dst = kb;  off = i - N; }
        else if (i < 3 * N)     { src = V;  dst = vb;  off = i - 2 * N; }
        else if (i < 3 * N + W) { src = wv; dst = wvf; off = i - 3 * N; }
        else                    { src = wo; dst = wof; off = i - 3 * N - W; }
        float4 a = *(const float4*)(src + off), b = *(const float4*)(src + off + 4);
        uint4 o;
        o.x = pack2(a.x, a.y); o.y = pack2(a.z, a.w);
        o.z = pack2(b.x, b.y); o.w = pack2(b.z, b.w);
        *(uint4*)(dst + off) = o;
    } else {
        const int mb = bid - CONVB;                       // 0..MASKB-1
        const size_t p0 = ((size_t)mb * 256 + tid) * 4;   // stored bit base (mult of 4)
        const int ing = (int)(p0 & 63);                   // in-group offset (mult of 4)
        const int nat = (((ing >> 4) & 1) << 5) | (((ing >> 2) & 3) << 3)
                      | (((ing >> 5) & 1) << 2);          // low 2 bits zero
        const int4 mv = *(const int4*)(m + ((p0 & ~(size_t)63) | (size_t)nat));
        unsigned nib = (unsigned)(mv.x != 0) | ((unsigned)(mv.y != 0) << 1)
                     | ((unsigned)(mv.z != 0) << 2) | ((unsigned)(mv.w != 0) << 3);
        unsigned long long bal0 = __ballot((nib & 1u) != 0);
        unsigned long long bal1 = __ballot((nib & 2u) != 0);
        unsigned long long bal2 = __ballot((nib & 4u) != 0);
        unsigned long long bal3 = __ballot((nib & 8u) != 0);
        const int lane = tid & 63, s = tid >> 6;
        const int sh8 = (lane & 7) * 8;                   // safe shift (<64)
        unsigned bb0 = (unsigned)(bal0 >> sh8) & 0xFFu;
        unsigned bb1 = (unsigned)(bal1 >> sh8) & 0xFFu;
        unsigned bb2 = (unsigned)(bal2 >> sh8) & 0xFFu;
        unsigned bb3 = (unsigned)(bal3 >> sh8) & 0xFFu;
        unsigned word = spread4(bb0) | (spread4(bb1) << 1)
                      | (spread4(bb2) << 2) | (spread4(bb3) << 3);
        if (lane < 8) mbits[(size_t)mb * 32 + s * 8 + lane] = word;
    }
}

// ---------------------------------------------------------------------------
// gemm_bt: 128x128 tile, BK=64, 4 waves. UPGRADED (T4+T2):
//  - counted vmcnt: stage kt+1, s_waitcnt vmcnt(8) (own wave's kt loads done,
//    kt+1's 8 stay in flight across a RAW s_barrier), compute, raw s_barrier.
//  - T2 swizzle both-sides (rule #21): source col = ((lane&7)^(lane>>3))*8
//    (bijective per 8-row chunk), ds_read addr XOR (q&7)<<4 — kills the
//    128B-stride 16-way bank conflict that counted-vmcnt would expose.
// EPI 1: acc+bias[row] -> vt tiles [B,H][kt:16][dk:64][128], XOR
// EPI 2: acc+bias[col] -> fp32 merged [M,N]
template <int EPI, int SWZ>
__global__ __launch_bounds__(256) void gemm_bt(const ushort_t* __restrict__ A,
                                               const ushort_t* __restrict__ B,
                                               const float* __restrict__ bias,
                                               void* __restrict__ outp,
                                               int Mdim, int Ndim, int Kdim) {
    __shared__ __align__(16) unsigned char As[2][16384];   // [buf][row:128][128B swz]
    __shared__ __align__(16) unsigned char Bs[2][16384];

    int bx = blockIdx.x, by = blockIdx.y;
    {
        int nwg = gridDim.x * gridDim.y;
        int L = by * gridDim.x + bx;
        int cpx = nwg >> 3;
        int orig = (L & 7) * cpx + (L >> 3);
        if constexpr (SWZ == 1) { bx = orig % gridDim.x; by = orig / gridDim.x; }
        else                    { by = orig % gridDim.y; bx = orig / gridDim.y; }
    }

    const int tid = threadIdx.x, lane = tid & 63, wave = tid >> 6;
    const int wr = wave >> 1, wc = wave & 1;
    const int q = lane & 15, g = lane >> 4;
    const int m0 = by * 128, n0 = bx * 128;

    // T2 pre-swizzled SOURCE: lane covers row strow (0-7 of chunk), col
    // elems ((lane&7)^strow)*8; LDS dest stays linear (chunk + lane*16).
    const int strow = lane >> 3;
    const int stcol = (((lane & 7) ^ strow) * 8);
    const ushort_t* Ab = A + (size_t)(m0 + strow) * Kdim + stcol;
    const ushort_t* Bb = B + (size_t)(n0 + strow) * Kdim + stcol;
    const int rswz = (q & 7) << 4;                 // read-side XOR (row&7 = q&7)

    f32x4 acc[4][4] = {};
    const int nK = Kdim >> 6;

#define STAGE(buf, k0)                                                          \
    {                                                                           \
        _Pragma("unroll")                                                       \
        for (int i = 0; i < 4; ++i) {                                           \
            const int ro = (wave * 4 + i) * 8;                                  \
            gl16(Ab + (size_t)ro * Kdim + (k0), As[buf] + (wave * 4 + i) * 1024); \
            gl16(Bb + (size_t)ro * Kdim + (k0), Bs[buf] + (wave * 4 + i) * 1024); \
        }                                                                       \
    }

    STAGE(0, 0);

    for (int kt = 0; kt < nK; ++kt) {
        const int cur = kt & 1;
        if (kt + 1 < nK) { STAGE(cur ^ 1, (kt + 1) << 6); wait_vm8(); }
        else             { wait_vm0(); }
        __builtin_amdgcn_s_barrier();              // tile kt fully in LDS (all waves)
#pragma unroll
        for (int s = 0; s < 2; ++s) {
            const int cb = s * 64 + g * 16;
            bf16x8 a[4], b[4];
#pragma unroll
            for (int m = 0; m < 4; ++m)
                a[m] = *(const bf16x8*)(As[cur] + (wr * 64 + m * 16 + q) * 128 + (cb ^ rswz));
#pragma unroll
            for (int n = 0; n < 4; ++n)
                b[n] = *(const bf16x8*)(Bs[cur] + (wc * 64 + n * 16 + q) * 128 + (cb ^ rswz));
#pragma unroll
            for (int m = 0; m < 4; ++m)
#pragma unroll
                for (int n = 0; n < 4; ++n)
                    acc[m][n] = mfma16(a[m], b[n], acc[m][n]);
        }
        __builtin_amdgcn_s_barrier();              // all reads of cur done -> reusable
    }
#undef STAGE

#pragma unroll
    for (int m = 0; m < 4; ++m)
#pragma unroll
        for (int n = 0; n < 4; ++n) {
            int gn = n0 + wc * 64 + n * 16 + q;
#pragma unroll
            for (int r = 0; r < 4; ++r) {
                int gm = m0 + wr * 64 + m * 16 + (g << 2) + r;
                float v = acc[m][n][r];
                if constexpr (EPI == 1) {
                    v += bias[gm];
                    int hh = gm >> 6, dk = gm & 63, b = gn >> 11, s = gn & 2047;
                    int kt2 = s >> 7, kloc = s & 127;
                    int eofs = ((kloc * 2) ^ ((dk & 7) << 4)) >> 1;
                    size_t idx = ((size_t)(b * Hc + hh)) * Sc * DKc + (size_t)kt2 * 8192 + dk * 128 + eofs;
                    ((unsigned short*)outp)[idx] = f2bf(v);
                } else {
                    v += bias[gn];
                    ((float*)outp)[(size_t)gm * Ndim + gn] = v;
                }
            }
        }
}

// ---------------------------------------------------------------------------
// gemm_qk256: qn+kn projections, 256x256 tile, 8 waves, same T4+T2 upgrade.
__global__ __launch_bounds__(512, 2) void gemm_qk256(const ushort_t* __restrict__ qb,
                                                     const ushort_t* __restrict__ wqf,
                                                     const float* __restrict__ bqf,
                                                     ushort_t* __restrict__ qnb,
                                                     const ushort_t* __restrict__ kb,
                                                     const ushort_t* __restrict__ wkf,
                                                     const float* __restrict__ bkf,
                                                     ushort_t* __restrict__ knb,
                                                     const float* __restrict__ temp) {
    __shared__ __align__(16) unsigned char As[2][32768];   // [buf][row:256][128B swz]
    __shared__ __align__(16) unsigned char Bs[2][32768];

    const int zz = blockIdx.z;
    const ushort_t* A = zz ? kb : qb;
    const ushort_t* B = zz ? wkf : wqf;
    const float* bias = zz ? bkf : bqf;

    int L = blockIdx.y * gridDim.x + blockIdx.x;    // x=4 (N tiles), y=32 (M tiles)
    int orig = (L & 7) * 16 + (L >> 3);
    int bx = orig & 3, by = orig >> 2;

    const int tid = threadIdx.x, lane = tid & 63, wave = tid >> 6;
    const int wr = wave >> 2, wc = wave & 3;        // 2 x 4 wave grid
    const int q = lane & 15, g = lane >> 4;
    const int m0 = by * 256, n0 = bx * 256;

    const int strow = lane >> 3;
    const int stcol = (((lane & 7) ^ strow) * 8);
    const ushort_t* Ab = A + (size_t)(m0 + strow) * Dc + stcol;
    const ushort_t* Bb = B + (size_t)(n0 + strow) * Dc + stcol;
    const int rswz = (q & 7) << 4;

    f32x4 acc[8][4] = {};
    constexpr int nK = Dc >> 6;   // 16

#define STAGE256(buf, k0)                                                       \
    {                                                                           \
        _Pragma("unroll")                                                       \
        for (int i = 0; i < 4; ++i) {                                           \
            const int j = wave * 4 + i;                                         \
            gl16(Ab + (size_t)(j * 8) * Dc + (k0), As[buf] + j * 1024);         \
            gl16(Bb + (size_t)(j * 8) * Dc + (k0), Bs[buf] + j * 1024);         \
        }                                                                       \
    }

    STAGE256(0, 0);

    for (int kt = 0; kt < nK; ++kt) {
        const int cur = kt & 1;
        if (kt + 1 < nK) { STAGE256(cur ^ 1, (kt + 1) << 6); wait_vm8(); }
        else             { wait_vm0(); }
        __builtin_amdgcn_s_barrier();
#pragma unroll
        for (int s = 0; s < 2; ++s) {
            const int cb = s * 64 + g * 16;
            bf16x8 a[8], b[4];
#pragma unroll
            for (int m = 0; m < 8; ++m)
                a[m] = *(const bf16x8*)(As[cur] + (wr * 128 + m * 16 + q) * 128 + (cb ^ rswz));
#pragma unroll
            for (int n = 0; n < 4; ++n)
                b[n] = *(const bf16x8*)(Bs[cur] + (wc * 64 + n * 16 + q) * 128 + (cb ^ rswz));
#pragma unroll
            for (int m = 0; m < 8; ++m)
#pragma unroll
                for (int n = 0; n < 4; ++n)
                    acc[m][n] = mfma16(a[m], b[n], acc[m][n]);
        }
        __builtin_amdgcn_s_barrier();
    }
#undef STAGE256

    // Epilogue. C/D layout: row=(lane>>4)*4+r, col=lane&15.
#pragma unroll
    for (int m = 0; m < 8; ++m)
#pragma unroll
        for (int n = 0; n < 4; ++n) {
            int gn = n0 + wc * 64 + n * 16 + q;
            float sc_h = 1.f;
            if (zz == 0) sc_h = 0.18033688011112042f * __builtin_amdgcn_rcpf(temp[gn >> 6]);
#pragma unroll
            for (int r = 0; r < 4; ++r) {
                int gm = m0 + wr * 128 + m * 16 + (g << 2) + r;
                float v = tanhf(acc[m][n][r] + bias[gn]);
                int b = gm >> 11, s = gm & 2047, hh = gn >> 6, dk = gn & 63;
                if (zz == 0) {
                    qnb[(((size_t)(b * Hc + hh)) * Sc + s) * DKc + dk] = f2bf(v * sc_h);
                } else {
                    int kt2 = s >> 7, nr = s & 127;
                    int prow = (nr & 64) | (((nr >> 5) & 1) << 4) | (((nr >> 3) & 3) << 2)
                             | (((nr >> 2) & 1) << 5) | (nr & 3);
                    int eofs = ((dk * 2) ^ ((prow & 7) << 4)) >> 1;
                    size_t idx = ((size_t)(b * Hc + hh)) * Sc * DKc + (size_t)kt2 * 8192 + prow * 64 + eofs;
                    knb[idx] = f2bf(v);
                }
            }
        }
}

// ---------------------------------------------------------------------------
// Flash attention (unchanged — issue-saturated at MfmaUtil+VALUBusy ~93%).
__global__ __launch_bounds__(512, 2) void attn_k(const ushort_t* __restrict__ qn,
                                                 const ushort_t* __restrict__ kn,
                                                 const ushort_t* __restrict__ vtp,
                                                 const unsigned* __restrict__ mbits,
                                                 ushort_t* __restrict__ ctxb) {
    __shared__ __align__(16) unsigned char Kl[2][16384];   // [buf][prow:128][128B swz]
    __shared__ __align__(16) unsigned char Vl[2][16384];   // [buf][dk:64][256B swz]

    const int tid = threadIdx.x, lane = tid & 63, wave = tid >> 6;
    const int q = lane & 15, g = lane >> 4;

    const int wg = blockIdx.x;
    const int orig = (wg & 7) * 64 + (wg >> 3);
    const int qt = orig & 7, h = (orig >> 3) & 15, b = orig >> 7;
    const int q0 = qt * 256;
    const int qr0 = q0 + wave * 32 + q;
    const size_t headoff = ((size_t)(b * Hc + h)) * Sc * DKc;

    const unsigned char* Ksrc = (const unsigned char*)(kn + headoff);
    const unsigned char* Vsrc = (const unsigned char*)(vtp + headoff);
    const int so = wave * 1024 + lane * 16;
    const int ld = wave * 1024;

    bf16x8 qf[2][2];
    {
        const ushort_t* p0 = qn + headoff + (size_t)qr0 * DKc + g * 8;
        qf[0][0] = *(const bf16x8*)p0;
        qf[0][1] = *(const bf16x8*)(p0 + 32);
        qf[1][0] = *(const bf16x8*)(p0 + 16 * DKc);
        qf[1][1] = *(const bf16x8*)(p0 + 16 * DKc + 32);
    }
    const unsigned* mr0 = mbits + ((size_t)b * Sc + qr0) * (Sc / 32);
    const unsigned* mr1 = mr0 + 16 * (Sc / 32);

    bf16x8 ones;
#pragma unroll
    for (int i = 0; i < 8; ++i) ones[i] = (__bf16)1.0f;

    f32x4 ctxa[2][4] = {};
    f32x4 lacc[2] = {};
    const int swz = (q & 7) << 4;
    const int sh = g << 2;

    gl16(Ksrc + so,        &Kl[0][ld]);
    gl16(Ksrc + 8192 + so, &Kl[0][8192 + ld]);
    gl16(Vsrc + so,        &Vl[0][ld]);
    gl16(Vsrc + 8192 + so, &Vl[0][8192 + ld]);
    __syncthreads();

    for (int kt = 0; kt < Sc / 128; ++kt) {
        const int cur = kt & 1;
        if (kt < Sc / 128 - 1) {
            const unsigned char* ks = Ksrc + (kt + 1) * 16384;
            const unsigned char* vs = Vsrc + (kt + 1) * 16384;
            gl16(ks + so,        &Kl[cur ^ 1][ld]);
            gl16(ks + 8192 + so, &Kl[cur ^ 1][8192 + ld]);
            gl16(vs + so,        &Vl[cur ^ 1][ld]);
            gl16(vs + 8192 + so, &Vl[cur ^ 1][8192 + ld]);
        }
        unsigned mwq[2][4];
        {
            uint4 t0 = *(const uint4*)(mr0 + kt * 4);
            uint4 t1 = *(const uint4*)(mr1 + kt * 4);
            mwq[0][0] = t0.x >> sh; mwq[0][1] = t0.y >> sh;
            mwq[0][2] = t0.z >> sh; mwq[0][3] = t0.w >> sh;
            mwq[1][0] = t1.x >> sh; mwq[1][1] = t1.y >> sh;
            mwq[1][2] = t1.z >> sh; mwq[1][3] = t1.w >> sh;
        }
        const unsigned char* Kb = Kl[cur];
        const unsigned char* Vb = Vl[cur];

#pragma unroll
        for (int kh = 0; kh < 2; ++kh) {
            f32x4 s0[4] = {}, s1[4] = {};
            __builtin_amdgcn_s_setprio(1);
#pragma unroll
            for (int f = 0; f < 4; ++f) {
                const int ro = (kh * 64 + f * 16 + q) * 128;
                bf16x8 a0 = *(const bf16x8*)(Kb + ro + ((g * 16) ^ swz));
                bf16x8 a1 = *(const bf16x8*)(Kb + ro + ((64 + g * 16) ^ swz));
                s0[f] = mfma16(a0, qf[0][0], s0[f]);
                s0[f] = mfma16(a1, qf[0][1], s0[f]);
                s1[f] = mfma16(a0, qf[1][0], s1[f]);
                s1[f] = mfma16(a1, qf[1][1], s1[f]);
            }
            __builtin_amdgcn_s_setprio(0);

#pragma unroll
            for (int f = 0; f < 4; ++f) {
                unsigned w0 = mwq[0][kh * 2 + (f >> 1)];
                unsigned w1 = mwq[1][kh * 2 + (f >> 1)];
#pragma unroll
                for (int r = 0; r < 4; ++r) {
                    const unsigned bitc = 1u << (((f & 1) << 4) + r);
                    float v0 = (w0 & bitc) ? s0[f][r] : -1e30f;
                    float v1 = (w1 & bitc) ? s1[f][r] : -1e30f;
                    s0[f][r] = __builtin_amdgcn_exp2f(v0);
                    s1[f][r] = __builtin_amdgcn_exp2f(v1);
                }
            }

            bf16x8 pa0[2], pa1[2];
#pragma unroll
            for (int cs = 0; cs < 2; ++cs)
#pragma unroll
                for (int r = 0; r < 4; ++r) {
                    pa0[cs][r]     = (__bf16)s0[cs][r];
                    pa0[cs][4 + r] = (__bf16)s0[cs + 2][r];
                    pa1[cs][r]     = (__bf16)s1[cs][r];
                    pa1[cs][4 + r] = (__bf16)s1[cs + 2][r];
                }

            __builtin_amdgcn_s_setprio(1);
#pragma unroll
            for (int cs = 0; cs < 2; ++cs) {
                const int csg = kh * 2 + cs;
                lacc[0] = mfma16(pa0[cs], ones, lacc[0]);
                lacc[1] = mfma16(pa1[cs], ones, lacc[1]);
#pragma unroll
                for (int j = 0; j < 4; ++j) {
                    bf16x8 vb = *(const bf16x8*)(Vb + (j * 16 + q) * 256 + ((csg * 64 + g * 16) ^ swz));
                    ctxa[0][j] = mfma16(pa0[cs], vb, ctxa[0][j]);
                    ctxa[1][j] = mfma16(pa1[cs], vb, ctxa[1][j]);
                }
            }
            __builtin_amdgcn_s_setprio(0);
        }
        __syncthreads();
    }

#pragma unroll
    for (int qg = 0; qg < 2; ++qg) {
        f32x4 linv;
#pragma unroll
        for (int r = 0; r < 4; ++r) linv[r] = __builtin_amdgcn_rcpf(lacc[qg][r]);
#pragma unroll
        for (int j = 0; j < 4; ++j)
#pragma unroll
            for (int r = 0; r < 4; ++r) {
                int srow = q0 + wave * 32 + qg * 16 + (g << 2) + r;
                int col = h * DKc + j * 16 + q;
                float v = ctxa[qg][j][r] * linv[r];
                ctxb[((size_t)b * Sc + srow) * Dc + col] = __builtin_bit_cast(unsigned short, (__bf16)v);
            }
    }
}

// ---------------------------------------------------------------------------
__global__ __launch_bounds__(256) void rmsnorm_k(float* __restrict__ out,
                                                 const float* __restrict__ w) {
    const int row = blockIdx.x, tid = threadIdx.x;
    float4* p = (float4*)(out + (size_t)row * Dc) + tid;
    float4 v = *p;
    float ss = v.x * v.x + v.y * v.y + v.z * v.z + v.w * v.w;
#pragma unroll
    for (int o = 32; o >= 1; o >>= 1) ss += __shfl_xor(ss, o);
    __shared__ float sm[4];
    if ((tid & 63) == 0) sm[tid >> 6] = ss;
    __syncthreads();
    float tot = sm[0] + sm[1] + sm[2] + sm[3];
    float r = rsqrtf(tot * (1.f / Dc) + 1e-8f);
    float4 wv = *((const float4*)w + tid);
    v.x *= r * wv.x; v.y *= r * wv.y; v.z *= r * wv.z; v.w *= r * wv.w;
    *p = v;
}

// ---------------------------------------------------------------------------
extern "C" void kernel_launch(void* const* d_in, const int* in_sizes, int n_in,
                              void* d_out, int out_size, void* d_ws, size_t ws_size,
                              hipStream_t stream) {
    (void)in_sizes; (void)n_in; (void)out_size; (void)ws_size;
    const float* Q    = (const float*)d_in[0];
    const float* K    = (const float*)d_in[1];
    const float* V    = (const float*)d_in[2];
    const int*   mask = (const int*)  d_in[3];
    const float* wq   = (const float*)d_in[4];
    const float* bq   = (const float*)d_in[5];
    const float* wk   = (const float*)d_in[6];
    const float* bk   = (const float*)d_in[7];
    const float* wv   = (const float*)d_in[8];
    const float* bv   = (const float*)d_in[9];
    const float* wo   = (const float*)d_in[10];
    const float* bo   = (const float*)d_in[11];
    const float* naqw = (const float*)d_in[12];
    const float* naqb = (const float*)d_in[13];
    const float* nakw = (const float*)d_in[14];
    const float* nakb = (const float*)d_in[15];
    const float* temp = (const float*)d_in[16];
    const float* rmsw = (const float*)d_in[17];

    char* ws = (char*)d_ws;
    size_t off = 0;
    auto take = [&](size_t n) { char* p = ws + off; off += (n + 255) & ~(size_t)255; return p; };
    unsigned short* vtb  = (unsigned short*)take((size_t)Mc * Dc * 2);
    unsigned short* qb   = (unsigned short*)take((size_t)Mc * Dc * 2);
    unsigned short* kb   = (unsigned short*)take((size_t)Mc * Dc * 2);
    unsigned short* vb   = (unsigned short*)take((size_t)Mc * Dc * 2);
    unsigned short* qnb  = (unsigned short*)take((size_t)Mc * Dc * 2);
    unsigned short* knb  = (unsigned short*)take((size_t)Mc * Dc * 2);
    unsigned short* wqf  = (unsigned short*)take((size_t)Dc * Dc * 2);
    unsigned short* wkf  = (unsigned short*)take((size_t)Dc * Dc * 2);
    unsigned short* wvf  = (unsigned short*)take((size_t)Dc * Dc * 2);
    unsigned short* wof  = (unsigned short*)take((size_t)Dc * Dc * 2);
    float*    bqf   = (float*)take(Dc * 4);
    float*    bkf   = (float*)take(Dc * 4);
    unsigned* mbits = (unsigned*)take((size_t)Bc * Sc * (Sc / 32) * 4);
    // alias (live ranges disjoint): ctxb reuses kb (kb dead after qk GEMM)
    unsigned short* ctxb = kb;

    fold_w2<<<dim3(4, 16, 3), 256, 0, stream>>>(naqw, wq, wqf, nakw, wk, wkf,
                                                bq, naqb, bqf, bk, nakb, bkf);
    conv_mask<<<dim3(CONVB + MASKB), 256, 0, stream>>>(Q, K, V, wv, wo,
                                                       qb, kb, vb, wvf, wof,
                                                       mask, mbits);

    // v^T = Wv @ V^T + bv   (tile layout for attn staging)
    gemm_bt<1, 2><<<dim3(Mc / 128, Dc / 128), 256, 0, stream>>>(
        wvf, vb, bv, vtb, Dc, Mc, Dc);
    // qn/kn projections, 256-sq tile (z=0: qn scaled; z=1: kn tiles)
    gemm_qk256<<<dim3(4, 32, 2), 512, 0, stream>>>(
        qb, wqf, bqf, qnb, kb, wkf, bkf, knb, temp);

    attn_k<<<dim3(512), 512, 0, stream>>>(qnb, knb, vtb, mbits, ctxb);

    // out = ctx @ wo^T + bo (fp32 into d_out), then in-place RMSNorm
    gemm_bt<2, 1><<<dim3(Dc / 128, Mc / 128), 256, 0, stream>>>(
        ctxb, wof, bo, d_out, Mc, Dc, Dc);
    rmsnorm_k<<<dim3(Mc), 256, 0, stream>>>((float*)d_out, rmsw);
}